// Round 17
// baseline (221.852 us; speedup 1.0000x reference)
//
#include <hip/hip_runtime.h>

#define B_SZ 2
#define S_LEN 2048
#define HID_DIM 2048
#define NHEADS 16
#define HEAD_D 128
#define WIN 1024
#define M_ROWS (B_SZ * S_LEN)
#define NXC 8388608  /* M_ROWS*HID_DIM */

typedef __attribute__((ext_vector_type(8))) short bf16x8;
typedef __attribute__((ext_vector_type(4))) float f32x4;

#define SCALE_F 0.08838834764831845f   /* 1/sqrt(128) */
#define SOFTCAP_F 30.0f

__device__ __forceinline__ unsigned short f2bf(float f) {
  unsigned u = __builtin_bit_cast(unsigned, f);
  unsigned r = (u + 0x7FFFu + ((u >> 16) & 1u)) >> 16;
  return (unsigned short)r;
}

__device__ __forceinline__ void vmwait5() { asm volatile("s_waitcnt vmcnt(5)" ::: "memory"); }
__device__ __forceinline__ void vmwait6() { asm volatile("s_waitcnt vmcnt(6)" ::: "memory"); }
__device__ __forceinline__ void vmwait0() { asm volatile("s_waitcnt vmcnt(0)" ::: "memory"); }
__device__ __forceinline__ void pbar()    { asm volatile("s_barrier" ::: "memory"); }

// ---------------- fused fp32 -> bf16 conversion (grid-stride, 2048 blocks) --
__global__ __launch_bounds__(256)
void cvt_all_kernel(const float* __restrict__ x,  const float* __restrict__ Wq,
                    const float* __restrict__ Wk, const float* __restrict__ Wv,
                    const float* __restrict__ Wo, unsigned short* __restrict__ dst) {
  const int a0 = 1048576;                                 // NX/8
  const int aw = 524288;                                  // NW/8
  const int total = a0 + 4 * aw;                          // 3145728
  const int stride = 2048 * 256;
  for (int i = blockIdx.x * 256 + threadIdx.x; i < total; i += stride) {
    const float* src;
    float scale = 1.0f;
    int j = i;
    if (i < a0) { src = x; }
    else if (i < a0 + aw)     { src = Wq; j = i - a0;          scale = SCALE_F / SOFTCAP_F; }
    else if (i < a0 + 2 * aw) { src = Wk; j = i - a0 - aw; }
    else if (i < a0 + 3 * aw) { src = Wv; j = i - a0 - 2 * aw; }
    else                      { src = Wo; j = i - a0 - 3 * aw; }
    const f32x4* p = (const f32x4*)src + (size_t)j * 2;
    f32x4 a = p[0], b = p[1];
    bf16x8 o;
    o[0] = (short)f2bf(a[0] * scale); o[1] = (short)f2bf(a[1] * scale);
    o[2] = (short)f2bf(a[2] * scale); o[3] = (short)f2bf(a[3] * scale);
    o[4] = (short)f2bf(b[0] * scale); o[5] = (short)f2bf(b[1] * scale);
    o[6] = (short)f2bf(b[2] * scale); o[7] = (short)f2bf(b[3] * scale);
    *((bf16x8*)dst + i) = o;
  }
}

// ---------------- async global->LDS 16B ----------------
__device__ __forceinline__ void gload16(const unsigned short* g, unsigned short* l) {
  __builtin_amdgcn_global_load_lds(
      (const __attribute__((address_space(1))) unsigned int*)g,
      (__attribute__((address_space(3))) unsigned int*)l, 16, 0, 0);
}

// ============ QKV GEMM (round-12 proven, 101us): BM=256 BN=384 BK=32 =======
__global__ __launch_bounds__(512, 2)
void gemm_qkv_kernel(const unsigned short* __restrict__ A,
                     const unsigned short* __restrict__ Bm,
                     unsigned short* __restrict__ Out) {
  extern __shared__ char smem[];
  constexpr int K = 2048, NT = 64;
  constexpr int SLOTW = 20480;          // shorts per slot (A 8192 + B 12288)
  const int t = threadIdx.x;
  const int w = t >> 6, l = t & 63, c = l & 15, g = l >> 4;
  const int wr = w >> 2, wc = w & 3;
  const int xcd = blockIdx.x & 7, i = blockIdx.x >> 3;
  const int nt = xcd * 2 + (i & 1), mt = i >> 1;
  const int m0 = mt * 256, n0 = nt * 384;
  const unsigned short* Ab = A + (size_t)m0 * K;
  const unsigned short* Bb = Bm + (size_t)n0 * K;

  int aoff[2], boff[3];
#pragma unroll
  for (int j = 0; j < 2; ++j) {
    int S = j * 512 + t, rp = S >> 3, slu = (S & 7) ^ (rp & 7);
    aoff[j] = (rp * 2 + (slu >> 2)) * K + (slu & 3) * 8;
  }
#pragma unroll
  for (int j = 0; j < 3; ++j) {
    int S = j * 512 + t, rp = S >> 3, slu = (S & 7) ^ (rp & 7);
    boff[j] = (rp * 2 + (slu >> 2)) * K + (slu & 3) * 8;
  }
  auto sbase = [&](int s) { return (unsigned short*)smem + s * SLOTW; };
  auto stA = [&](int tt, int s, int j) {
    gload16(Ab + aoff[j] + tt * 32, sbase(s) + (j * 512 + t) * 8);
  };
  auto stB = [&](int tt, int s, int j) {
    gload16(Bb + boff[j] + tt * 32, sbase(s) + 8192 + (j * 512 + t) * 8);
  };
  auto rix = [&](int row) {
    return (row >> 1) * 64 + (((((row & 1) << 2) | g) ^ ((row >> 1) & 7)) * 8);
  };

  f32x4 acc[8][6];
#pragma unroll
  for (int mi = 0; mi < 8; ++mi)
#pragma unroll
    for (int nf = 0; nf < 6; ++nf) acc[mi][nf] = (f32x4)0.0f;

  stA(0, 0, 0); stA(0, 0, 1); stB(0, 0, 0); stB(0, 0, 1); stB(0, 0, 2);
  stA(1, 1, 0); stA(1, 1, 1); stB(1, 1, 0); stB(1, 1, 1); stB(1, 1, 2);
  vmwait5();
  pbar();

#pragma unroll 1
  for (int tt = 0; tt < NT; ++tt) {
    const int s = tt & 3, ns = (tt + 2) & 3;
    const bool pre = (tt + 2) < NT;
    unsigned short* sA = sbase(s);
    unsigned short* sB = sA + 8192;

    bf16x8 af[8], bf[2];
#pragma unroll
    for (int mi = 0; mi < 8; ++mi) af[mi] = *(const bf16x8*)&sA[rix(wr * 128 + mi * 16 + c)];
#pragma unroll
    for (int nf = 0; nf < 2; ++nf) bf[nf] = *(const bf16x8*)&sB[rix(wc * 96 + nf * 16 + c)];
    if (pre) { stA(tt + 2, ns, 0); stA(tt + 2, ns, 1); }
    pbar();
    __builtin_amdgcn_s_setprio(1);
#pragma unroll
    for (int mi = 0; mi < 8; ++mi)
#pragma unroll
      for (int nf = 0; nf < 2; ++nf)
        acc[mi][nf] = __builtin_amdgcn_mfma_f32_16x16x32_bf16(af[mi], bf[nf], acc[mi][nf], 0, 0, 0);
    __builtin_amdgcn_s_setprio(0);
    pbar();

#pragma unroll
    for (int nf = 0; nf < 2; ++nf) bf[nf] = *(const bf16x8*)&sB[rix(wc * 96 + (2 + nf) * 16 + c)];
    if (pre) { stB(tt + 2, ns, 0); stB(tt + 2, ns, 1); }
    pbar();
    __builtin_amdgcn_s_setprio(1);
#pragma unroll
    for (int mi = 0; mi < 8; ++mi)
#pragma unroll
      for (int nf = 0; nf < 2; ++nf)
        acc[mi][2 + nf] = __builtin_amdgcn_mfma_f32_16x16x32_bf16(af[mi], bf[nf], acc[mi][2 + nf], 0, 0, 0);
    __builtin_amdgcn_s_setprio(0);
    pbar();

#pragma unroll
    for (int nf = 0; nf < 2; ++nf) bf[nf] = *(const bf16x8*)&sB[rix(wc * 96 + (4 + nf) * 16 + c)];
    if (pre) { stB(tt + 2, ns, 2); }
    pbar();
    __builtin_amdgcn_s_setprio(1);
#pragma unroll
    for (int mi = 0; mi < 8; ++mi)
#pragma unroll
      for (int nf = 0; nf < 2; ++nf)
        acc[mi][4 + nf] = __builtin_amdgcn_mfma_f32_16x16x32_bf16(af[mi], bf[nf], acc[mi][4 + nf], 0, 0, 0);
    __builtin_amdgcn_s_setprio(0);
    if (pre) vmwait5(); else vmwait0();
    pbar();
  }

#pragma unroll
  for (int mi = 0; mi < 8; ++mi)
#pragma unroll
    for (int nf = 0; nf < 6; ++nf)
#pragma unroll
      for (int r = 0; r < 4; ++r) {
        int row = m0 + wr * 128 + mi * 16 + g * 4 + r;
        int col = n0 + wc * 96 + nf * 16 + c;
        int which = col >> 11;
        Out[(size_t)which * NXC + (size_t)row * 2048 + (col & 2047)] = f2bf(acc[mi][nf][r]);
      }
}

// ============ Wo GEMM (known-good): BM=128 BN=256 BK=64 ====================
__global__ __launch_bounds__(512, 2)
void gemm_wo_kernel(const unsigned short* __restrict__ A,
                    const unsigned short* __restrict__ Bm,
                    float* __restrict__ Out) {
  extern __shared__ char smem[];
  constexpr int K = 2048, NT = 32;
  constexpr int SLOT = 49152;
  const int t = threadIdx.x;
  const int w = t >> 6, l = t & 63, c = l & 15, g = l >> 4;
  const int wr = w >> 2, wc = w & 3;
  const int xcd = blockIdx.x & 7, q = blockIdx.x >> 3;
  const int mt = q, nt = xcd;
  const int m0 = mt * 128, n0 = nt * 256;
  const unsigned short* Ab = A + (size_t)m0 * K;
  const unsigned short* Bb = Bm + (size_t)n0 * K;

  auto lA = [&](int s) { return (unsigned short*)(smem + s * SLOT); };
  auto lB = [&](int s) { return (unsigned short*)(smem + s * SLOT + 16384); };
  auto stA = [&](int tt, int s, int j) {
    int chunk = j * 512 + t, row = chunk >> 3, ch = chunk & 7;
    gload16(Ab + (size_t)row * K + tt * 64 + ((ch ^ (row & 7)) * 8), lA(s) + chunk * 8);
  };
  auto stB = [&](int tt, int s, int j) {
    int chunk = j * 512 + t, row = chunk >> 3, ch = chunk & 7;
    gload16(Bb + (size_t)row * K + tt * 64 + ((ch ^ (row & 7)) * 8), lB(s) + chunk * 8);
  };
  auto rdA = [&](unsigned short* base, int mi, int kk) {
    int row = wr * 64 + mi * 16 + c;
    int ch = (kk * 4 + g) ^ (row & 7);
    return *(const bf16x8*)&base[row * 64 + ch * 8];
  };
  auto rdB = [&](unsigned short* base, int nf, int kk) {
    int row = wc * 64 + nf * 16 + c;
    int ch = (kk * 4 + g) ^ (row & 7);
    return *(const bf16x8*)&base[row * 64 + ch * 8];
  };

  f32x4 acc[4][4];
#pragma unroll
  for (int i = 0; i < 4; ++i)
#pragma unroll
    for (int j = 0; j < 4; ++j) acc[i][j] = (f32x4)0.0f;

  stA(0, 0, 0); stA(0, 0, 1);
  stB(0, 0, 0); stB(0, 0, 1); stB(0, 0, 2); stB(0, 0, 3);
  stA(1, 1, 0); stA(1, 1, 1);
  stB(1, 1, 0); stB(1, 1, 1); stB(1, 1, 2); stB(1, 1, 3);
  vmwait6();
  pbar();

#pragma unroll 1
  for (int tt = 0; tt < NT; ++tt) {
    const int s = tt % 3, ns = (tt + 2) % 3;
    unsigned short* sA = lA(s);
    unsigned short* sB = lB(s);
    const bool pre = (tt + 2) < NT;

    bf16x8 af[4][2], bfr[2][2];
#pragma unroll
    for (int mi = 0; mi < 4; ++mi)
#pragma unroll
      for (int kk = 0; kk < 2; ++kk) af[mi][kk] = rdA(sA, mi, kk);
#pragma unroll
    for (int ni = 0; ni < 2; ++ni)
#pragma unroll
      for (int kk = 0; kk < 2; ++kk) bfr[ni][kk] = rdB(sB, ni, kk);
    if (pre) { stA(tt + 2, ns, 0); stA(tt + 2, ns, 1); stB(tt + 2, ns, 0); }
    pbar();
    __builtin_amdgcn_s_setprio(1);
#pragma unroll
    for (int kk = 0; kk < 2; ++kk)
#pragma unroll
      for (int mi = 0; mi < 4; ++mi)
#pragma unroll
        for (int ni = 0; ni < 2; ++ni)
          acc[mi][ni] = __builtin_amdgcn_mfma_f32_16x16x32_bf16(af[mi][kk], bfr[ni][kk],
                                                                acc[mi][ni], 0, 0, 0);
    __builtin_amdgcn_s_setprio(0);
    pbar();

#pragma unroll
    for (int ni = 0; ni < 2; ++ni)
#pragma unroll
      for (int kk = 0; kk < 2; ++kk) bfr[ni][kk] = rdB(sB, 2 + ni, kk);
    if (pre) { stB(tt + 2, ns, 1); stB(tt + 2, ns, 2); stB(tt + 2, ns, 3); }
    pbar();
    __builtin_amdgcn_s_setprio(1);
#pragma unroll
    for (int kk = 0; kk < 2; ++kk)
#pragma unroll
      for (int mi = 0; mi < 4; ++mi)
#pragma unroll
        for (int ni = 0; ni < 2; ++ni)
          acc[mi][2 + ni] = __builtin_amdgcn_mfma_f32_16x16x32_bf16(af[mi][kk], bfr[ni][kk],
                                                                    acc[mi][2 + ni], 0, 0, 0);
    __builtin_amdgcn_s_setprio(0);
    if (pre) vmwait6(); else vmwait0();
    pbar();
  }

#pragma unroll
  for (int mi = 0; mi < 4; ++mi)
#pragma unroll
    for (int nf = 0; nf < 4; ++nf)
#pragma unroll
      for (int r = 0; r < 4; ++r) {
        int row = m0 + wr * 64 + mi * 16 + g * 4 + r;
        int col = n0 + wc * 64 + nf * 16 + c;
        Out[(size_t)row * 2048 + col] = acc[mi][nf][r];
      }
}

// ---------------- flash attention: swapped QK^T + b64 packed P-writes ------
// (round-12 proven config: KVBLK=64, ones-MFMA denominator)
__global__ __launch_bounds__(256, 2)
void attn_kernel(const unsigned short* __restrict__ Qb,
                 const unsigned short* __restrict__ Kb,
                 const unsigned short* __restrict__ Vb,
                 unsigned short* __restrict__ Ob) {
  __shared__ unsigned short K_lds[64 * HEAD_D];
  __shared__ unsigned short V_lds[HEAD_D * 64];
  __shared__ unsigned short P_lds[4][32 * 64];

  const int t = threadIdx.x;
  const int w = t >> 6, l = t & 63;
  const int g = l >> 4, c = l & 15;

  const int bid = blockIdx.x;
  const int widx = (bid & 7) * 64 + (bid >> 3);
  const int bh = widx >> 4;
  const int q0 = (widx & 15) * 128;
  const int b = bh >> 4, h = bh & 15;
  const size_t base = (size_t)b * S_LEN * HID_DIM + (size_t)h * HEAD_D;
  const int qw = q0 + w * 32;

  bf16x8 qf[2][4];
#pragma unroll
  for (int qh = 0; qh < 2; ++qh) {
    const unsigned short* qp = Qb + base + (size_t)(qw + qh * 16 + c) * HID_DIM + g * 8;
#pragma unroll
    for (int dch = 0; dch < 4; ++dch) qf[qh][dch] = *(const bf16x8*)(qp + dch * 32);
  }

  f32x4 acc[2][8];
#pragma unroll
  for (int qh = 0; qh < 2; ++qh)
#pragma unroll
    for (int dc = 0; dc < 8; ++dc) acc[qh][dc] = (f32x4)0.0f;
  f32x4 asum[2];
  asum[0] = (f32x4)0.0f; asum[1] = (f32x4)0.0f;
  bf16x8 ones;
#pragma unroll
  for (int j = 0; j < 8; ++j) ones[j] = (short)0x3F80;  // bf16 1.0

  int kstart = q0 - (WIN - 1);
  if (kstart < 0) kstart = 0;
  kstart &= ~63;
  const int kend = q0 + 127;

  const float C1 = -1.0f / 3.0f;
  const float CE = SOFTCAP_F * 1.4426950408889634f;

  for (int k0 = kstart; k0 <= kend; k0 += 64) {
#pragma unroll
    for (int i = 0; i < 4; ++i) {
      int li = i * 256 + t;
      int row = li >> 4, chs = li & 15;
      int ch = chs ^ (row & 7);
      gload16(Kb + base + (size_t)(k0 + row) * HID_DIM + ch * 8, &K_lds[li * 8]);
    }
    {
      int m4 = t >> 4, ch = t & 15;
      const unsigned short* vg = Vb + base + (size_t)(k0 + 4 * m4) * HID_DIM + ch * 8;
      bf16x8 v0 = *(const bf16x8*)vg;
      bf16x8 v1 = *(const bf16x8*)(vg + HID_DIM);
      bf16x8 v2 = *(const bf16x8*)(vg + 2 * HID_DIM);
      bf16x8 v3 = *(const bf16x8*)(vg + 3 * HID_DIM);
#pragma unroll
      for (int j = 0; j < 8; ++j) {
        int d = ch * 8 + j;
        int sw = (j ^ ch) & 7;
        int e = (d * 64 + 4 * m4) ^ (sw << 3);
        unsigned long long val =
            (unsigned long long)(unsigned short)v0[j] |
            ((unsigned long long)(unsigned short)v1[j] << 16) |
            ((unsigned long long)(unsigned short)v2[j] << 32) |
            ((unsigned long long)(unsigned short)v3[j] << 48);
        *(unsigned long long*)&V_lds[e] = val;
      }
    }
    __syncthreads();

    if (k0 <= qw + 31 && k0 + 63 >= qw - (WIN - 1)) {
      // ---- QK^T SWAPPED: sc[qh][kc][r] = S[key = k0+kc*16+g*4+r][q = qw+qh*16+c]
      f32x4 sc[2][4];
#pragma unroll
      for (int qh = 0; qh < 2; ++qh)
#pragma unroll
        for (int kc = 0; kc < 4; ++kc) sc[qh][kc] = (f32x4)0.0f;
#pragma unroll
      for (int kc = 0; kc < 4; ++kc) {
#pragma unroll
        for (int dch = 0; dch < 4; ++dch) {
          int row = kc * 16 + c;
          int e = (row * HEAD_D + dch * 32 + g * 8) ^ ((row & 7) << 3);
          bf16x8 kf = *(const bf16x8*)&K_lds[e];
#pragma unroll
          for (int qh = 0; qh < 2; ++qh)
            sc[qh][kc] = __builtin_amdgcn_mfma_f32_16x16x32_bf16(kf, qf[qh][dch],
                                                                 sc[qh][kc], 0, 0, 0);
        }
      }
      // ---- softcap + mask + packed b64 P store ----
#pragma unroll
      for (int qh = 0; qh < 2; ++qh) {
        const int qwh = qw + qh * 16;
        const int i_g = qwh + c;
        const bool full = (k0 + 63 <= qwh) && (qwh + 15 - k0 < WIN);
        const int qq = qh * 16 + c;
#pragma unroll
        for (int kc = 0; kc < 4; ++kc) {
          unsigned u[4];
#pragma unroll
          for (int r = 0; r < 4; ++r) {
            float y = sc[qh][kc][r];
            float y2 = y * y;
            float tpoly = y * __builtin_fmaf(y2, C1, 1.0f);
            float pv = __builtin_amdgcn_exp2f(__builtin_fmaf(tpoly, CE, -CE));
            if (!full) {
              int j_g = k0 + kc * 16 + g * 4 + r;
              bool okm = (j_g <= i_g) && (i_g - j_g < WIN);
              pv = okm ? pv : 0.0f;
            }
            u[r] = __builtin_bit_cast(unsigned, pv);
          }
          unsigned w0 = (u[0] >> 16) | (u[1] & 0xFFFF0000u);
          unsigned w1 = (u[2] >> 16) | (u[3] & 0xFFFF0000u);
          int e = (qq * 64 + kc * 16 + g * 4) ^ ((qq & 7) << 3);
          *(unsigned long long*)&P_lds[w][e] =
              (unsigned long long)w0 | ((unsigned long long)w1 << 32);
        }
      }
      bf16x8 pa[2][2];
#pragma unroll
      for (int qh = 0; qh < 2; ++qh)
#pragma unroll
        for (int kb = 0; kb < 2; ++kb) {
          int row = qh * 16 + c;
          int e = (row * 64 + kb * 32 + g * 8) ^ ((row & 7) << 3);
          pa[qh][kb] = *(const bf16x8*)&P_lds[w][e];
        }
      // denominator: ones-column MFMA -> every lane gets the row sum
#pragma unroll
      for (int qh = 0; qh < 2; ++qh)
#pragma unroll
        for (int kb = 0; kb < 2; ++kb)
          asum[qh] = __builtin_amdgcn_mfma_f32_16x16x32_bf16(pa[qh][kb], ones,
                                                             asum[qh], 0, 0, 0);
#pragma unroll
      for (int dc = 0; dc < 8; ++dc) {
#pragma unroll
        for (int kb = 0; kb < 2; ++kb) {
          int d = dc * 16 + c;
          int sw = ((d & 7) ^ ((d >> 3) & 7)) & 7;
          int e = (d * 64 + kb * 32 + g * 8) ^ (sw << 3);
          bf16x8 vf = *(const bf16x8*)&V_lds[e];
#pragma unroll
          for (int qh = 0; qh < 2; ++qh)
            acc[qh][dc] = __builtin_amdgcn_mfma_f32_16x16x32_bf16(pa[qh][kb], vf,
                                                                  acc[qh][dc], 0, 0, 0);
        }
      }
    }
    __syncthreads();
  }

#pragma unroll
  for (int qh = 0; qh < 2; ++qh)
#pragma unroll
    for (int r = 0; r < 4; ++r) {
      float rinv = 1.0f / asum[qh][r];
#pragma unroll
      for (int dc = 0; dc < 8; ++dc) {
        int qq = qw + qh * 16 + g * 4 + r;
        float o = acc[qh][dc][r] * rinv;
        Ob[base + (size_t)qq * HID_DIM + dc * 16 + c] = f2bf(o);
      }
    }
}

// ---------------- host launch ----------------
extern "C" void kernel_launch(void* const* d_in, const int* in_sizes, int n_in,
                              void* d_out, int out_size, void* d_ws, size_t ws_size,
                              hipStream_t stream) {
  const float* x  = (const float*)d_in[0];
  const float* Wq = (const float*)d_in[1];
  const float* Wk = (const float*)d_in[2];
  const float* Wv = (const float*)d_in[3];
  const float* Wo = (const float*)d_in[4];

  const size_t NX = (size_t)M_ROWS * HID_DIM;    // 8,388,608
  const size_t NW = (size_t)HID_DIM * HID_DIM;   // 4,194,304

  unsigned short* xb  = (unsigned short*)d_ws;
  unsigned short* Wqb = xb + NX;
  unsigned short* Wkb = Wqb + NW;   // contiguous (fused-QKV B matrix)
  unsigned short* Wvb = Wkb + NW;
  unsigned short* Wob = Wvb + NW;
  unsigned short* Qb  = Wob + NW;   // Qb,Kb,Vb contiguous (QKV epilogue routing)
  unsigned short* Kb  = Qb + NX;
  unsigned short* Vb  = Kb + NX;
  unsigned short* Ab  = xb;         // reuse x_bf16 region for attn output

  // 1) fused conversion (grid-stride, 2048 blocks = 8/CU)
  cvt_all_kernel<<<dim3(2048), 256, 0, stream>>>(x, Wq, Wk, Wv, Wo, xb);

  // 2) fused QKV projection: [4096,2048] x [6144,2048]^T, 256 blocks = 1 round
  gemm_qkv_kernel<<<dim3(256), 512, 163840, stream>>>(xb, Wqb, Qb);

  // 3) attention (512 blocks, XCD-chunked inside)
  attn_kernel<<<dim3(512), 256, 0, stream>>>(Qb, Kb, Vb, Ab);

  // 4) output projection: 256 blocks = 1 round
  gemm_wo_kernel<<<dim3(256), 512, 147456, stream>>>(Ab, Wob, (float*)d_out);
}

// Round 18
// 215.376 us; speedup vs baseline: 1.0301x; 1.0301x over previous
//
#include <hip/hip_runtime.h>

#define B_SZ 2
#define S_LEN 2048
#define HID_DIM 2048
#define NHEADS 16
#define HEAD_D 128
#define WIN 1024
#define M_ROWS (B_SZ * S_LEN)
#define NXC 8388608  /* M_ROWS*HID_DIM */

typedef __attribute__((ext_vector_type(8))) short bf16x8;
typedef __attribute__((ext_vector_type(4))) float f32x4;

#define SCALE_F 0.08838834764831845f   /* 1/sqrt(128) */
#define SOFTCAP_F 30.0f

__device__ __forceinline__ unsigned short f2bf(float f) {
  unsigned u = __builtin_bit_cast(unsigned, f);
  unsigned r = (u + 0x7FFFu + ((u >> 16) & 1u)) >> 16;
  return (unsigned short)r;
}

__device__ __forceinline__ void vmwait5() { asm volatile("s_waitcnt vmcnt(5)" ::: "memory"); }
__device__ __forceinline__ void vmwait6() { asm volatile("s_waitcnt vmcnt(6)" ::: "memory"); }
__device__ __forceinline__ void vmwait0() { asm volatile("s_waitcnt vmcnt(0)" ::: "memory"); }
__device__ __forceinline__ void pbar()    { asm volatile("s_barrier" ::: "memory"); }

// ---------------- fused fp32 -> bf16 conversion (flat, one launch) ----------
__global__ __launch_bounds__(256)
void cvt_all_kernel(const float* __restrict__ x,  const float* __restrict__ Wq,
                    const float* __restrict__ Wk, const float* __restrict__ Wv,
                    const float* __restrict__ Wo, unsigned short* __restrict__ dst) {
  const int i = blockIdx.x * 256 + threadIdx.x;           // i < 3145728
  const int a0 = 1048576;                                 // NX/8
  const int aw = 524288;                                  // NW/8
  const float* src;
  float scale = 1.0f;
  int j = i;
  if (i < a0) { src = x; }
  else if (i < a0 + aw)     { src = Wq; j = i - a0;          scale = SCALE_F / SOFTCAP_F; }
  else if (i < a0 + 2 * aw) { src = Wk; j = i - a0 - aw; }
  else if (i < a0 + 3 * aw) { src = Wv; j = i - a0 - 2 * aw; }
  else                      { src = Wo; j = i - a0 - 3 * aw; }
  const f32x4* p = (const f32x4*)src + (size_t)j * 2;
  f32x4 a = p[0], b = p[1];
  bf16x8 o;
  o[0] = (short)f2bf(a[0] * scale); o[1] = (short)f2bf(a[1] * scale);
  o[2] = (short)f2bf(a[2] * scale); o[3] = (short)f2bf(a[3] * scale);
  o[4] = (short)f2bf(b[0] * scale); o[5] = (short)f2bf(b[1] * scale);
  o[6] = (short)f2bf(b[2] * scale); o[7] = (short)f2bf(b[3] * scale);
  *((bf16x8*)dst + i) = o;
}

// ---------------- async global->LDS 16B ----------------
__device__ __forceinline__ void gload16(const unsigned short* g, unsigned short* l) {
  __builtin_amdgcn_global_load_lds(
      (const __attribute__((address_space(1))) unsigned int*)g,
      (__attribute__((address_space(3))) unsigned int*)l, 16, 0, 0);
}

// ============ QKV GEMM (round-12 proven, 101us): BM=256 BN=384 BK=32 =======
__global__ __launch_bounds__(512, 2)
void gemm_qkv_kernel(const unsigned short* __restrict__ A,
                     const unsigned short* __restrict__ Bm,
                     unsigned short* __restrict__ Out) {
  extern __shared__ char smem[];
  constexpr int K = 2048, NT = 64;
  constexpr int SLOTW = 20480;          // shorts per slot (A 8192 + B 12288)
  const int t = threadIdx.x;
  const int w = t >> 6, l = t & 63, c = l & 15, g = l >> 4;
  const int wr = w >> 2, wc = w & 3;
  const int xcd = blockIdx.x & 7, i = blockIdx.x >> 3;
  const int nt = xcd * 2 + (i & 1), mt = i >> 1;
  const int m0 = mt * 256, n0 = nt * 384;
  const unsigned short* Ab = A + (size_t)m0 * K;
  const unsigned short* Bb = Bm + (size_t)n0 * K;

  int aoff[2], boff[3];
#pragma unroll
  for (int j = 0; j < 2; ++j) {
    int S = j * 512 + t, rp = S >> 3, slu = (S & 7) ^ (rp & 7);
    aoff[j] = (rp * 2 + (slu >> 2)) * K + (slu & 3) * 8;
  }
#pragma unroll
  for (int j = 0; j < 3; ++j) {
    int S = j * 512 + t, rp = S >> 3, slu = (S & 7) ^ (rp & 7);
    boff[j] = (rp * 2 + (slu >> 2)) * K + (slu & 3) * 8;
  }
  auto sbase = [&](int s) { return (unsigned short*)smem + s * SLOTW; };
  auto stA = [&](int tt, int s, int j) {
    gload16(Ab + aoff[j] + tt * 32, sbase(s) + (j * 512 + t) * 8);
  };
  auto stB = [&](int tt, int s, int j) {
    gload16(Bb + boff[j] + tt * 32, sbase(s) + 8192 + (j * 512 + t) * 8);
  };
  auto rix = [&](int row) {
    return (row >> 1) * 64 + (((((row & 1) << 2) | g) ^ ((row >> 1) & 7)) * 8);
  };

  f32x4 acc[8][6];
#pragma unroll
  for (int mi = 0; mi < 8; ++mi)
#pragma unroll
    for (int nf = 0; nf < 6; ++nf) acc[mi][nf] = (f32x4)0.0f;

  stA(0, 0, 0); stA(0, 0, 1); stB(0, 0, 0); stB(0, 0, 1); stB(0, 0, 2);
  stA(1, 1, 0); stA(1, 1, 1); stB(1, 1, 0); stB(1, 1, 1); stB(1, 1, 2);
  vmwait5();
  pbar();

#pragma unroll 1
  for (int tt = 0; tt < NT; ++tt) {
    const int s = tt & 3, ns = (tt + 2) & 3;
    const bool pre = (tt + 2) < NT;
    unsigned short* sA = sbase(s);
    unsigned short* sB = sA + 8192;

    bf16x8 af[8], bf[2];
#pragma unroll
    for (int mi = 0; mi < 8; ++mi) af[mi] = *(const bf16x8*)&sA[rix(wr * 128 + mi * 16 + c)];
#pragma unroll
    for (int nf = 0; nf < 2; ++nf) bf[nf] = *(const bf16x8*)&sB[rix(wc * 96 + nf * 16 + c)];
    if (pre) { stA(tt + 2, ns, 0); stA(tt + 2, ns, 1); }
    pbar();
    __builtin_amdgcn_s_setprio(1);
#pragma unroll
    for (int mi = 0; mi < 8; ++mi)
#pragma unroll
      for (int nf = 0; nf < 2; ++nf)
        acc[mi][nf] = __builtin_amdgcn_mfma_f32_16x16x32_bf16(af[mi], bf[nf], acc[mi][nf], 0, 0, 0);
    __builtin_amdgcn_s_setprio(0);
    pbar();

#pragma unroll
    for (int nf = 0; nf < 2; ++nf) bf[nf] = *(const bf16x8*)&sB[rix(wc * 96 + (2 + nf) * 16 + c)];
    if (pre) { stB(tt + 2, ns, 0); stB(tt + 2, ns, 1); }
    pbar();
    __builtin_amdgcn_s_setprio(1);
#pragma unroll
    for (int mi = 0; mi < 8; ++mi)
#pragma unroll
      for (int nf = 0; nf < 2; ++nf)
        acc[mi][2 + nf] = __builtin_amdgcn_mfma_f32_16x16x32_bf16(af[mi], bf[nf], acc[mi][2 + nf], 0, 0, 0);
    __builtin_amdgcn_s_setprio(0);
    pbar();

#pragma unroll
    for (int nf = 0; nf < 2; ++nf) bf[nf] = *(const bf16x8*)&sB[rix(wc * 96 + (4 + nf) * 16 + c)];
    if (pre) { stB(tt + 2, ns, 2); }
    pbar();
    __builtin_amdgcn_s_setprio(1);
#pragma unroll
    for (int mi = 0; mi < 8; ++mi)
#pragma unroll
      for (int nf = 0; nf < 2; ++nf)
        acc[mi][4 + nf] = __builtin_amdgcn_mfma_f32_16x16x32_bf16(af[mi], bf[nf], acc[mi][4 + nf], 0, 0, 0);
    __builtin_amdgcn_s_setprio(0);
    if (pre) vmwait5(); else vmwait0();
    pbar();
  }

#pragma unroll
  for (int mi = 0; mi < 8; ++mi)
#pragma unroll
    for (int nf = 0; nf < 6; ++nf)
#pragma unroll
      for (int r = 0; r < 4; ++r) {
        int row = m0 + wr * 128 + mi * 16 + g * 4 + r;
        int col = n0 + wc * 96 + nf * 16 + c;
        int which = col >> 11;
        Out[(size_t)which * NXC + (size_t)row * 2048 + (col & 2047)] = f2bf(acc[mi][nf][r]);
      }
}

// ============ Wo GEMM (known-good): BM=128 BN=256 BK=64 ====================
__global__ __launch_bounds__(512, 2)
void gemm_wo_kernel(const unsigned short* __restrict__ A,
                    const unsigned short* __restrict__ Bm,
                    float* __restrict__ Out) {
  extern __shared__ char smem[];
  constexpr int K = 2048, NT = 32;
  constexpr int SLOT = 49152;
  const int t = threadIdx.x;
  const int w = t >> 6, l = t & 63, c = l & 15, g = l >> 4;
  const int wr = w >> 2, wc = w & 3;
  const int xcd = blockIdx.x & 7, q = blockIdx.x >> 3;
  const int mt = q, nt = xcd;
  const int m0 = mt * 128, n0 = nt * 256;
  const unsigned short* Ab = A + (size_t)m0 * K;
  const unsigned short* Bb = Bm + (size_t)n0 * K;

  auto lA = [&](int s) { return (unsigned short*)(smem + s * SLOT); };
  auto lB = [&](int s) { return (unsigned short*)(smem + s * SLOT + 16384); };
  auto stA = [&](int tt, int s, int j) {
    int chunk = j * 512 + t, row = chunk >> 3, ch = chunk & 7;
    gload16(Ab + (size_t)row * K + tt * 64 + ((ch ^ (row & 7)) * 8), lA(s) + chunk * 8);
  };
  auto stB = [&](int tt, int s, int j) {
    int chunk = j * 512 + t, row = chunk >> 3, ch = chunk & 7;
    gload16(Bb + (size_t)row * K + tt * 64 + ((ch ^ (row & 7)) * 8), lB(s) + chunk * 8);
  };
  auto rdA = [&](unsigned short* base, int mi, int kk) {
    int row = wr * 64 + mi * 16 + c;
    int ch = (kk * 4 + g) ^ (row & 7);
    return *(const bf16x8*)&base[row * 64 + ch * 8];
  };
  auto rdB = [&](unsigned short* base, int nf, int kk) {
    int row = wc * 64 + nf * 16 + c;
    int ch = (kk * 4 + g) ^ (row & 7);
    return *(const bf16x8*)&base[row * 64 + ch * 8];
  };

  f32x4 acc[4][4];
#pragma unroll
  for (int i = 0; i < 4; ++i)
#pragma unroll
    for (int j = 0; j < 4; ++j) acc[i][j] = (f32x4)0.0f;

  stA(0, 0, 0); stA(0, 0, 1);
  stB(0, 0, 0); stB(0, 0, 1); stB(0, 0, 2); stB(0, 0, 3);
  stA(1, 1, 0); stA(1, 1, 1);
  stB(1, 1, 0); stB(1, 1, 1); stB(1, 1, 2); stB(1, 1, 3);
  vmwait6();
  pbar();

#pragma unroll 1
  for (int tt = 0; tt < NT; ++tt) {
    const int s = tt % 3, ns = (tt + 2) % 3;
    unsigned short* sA = lA(s);
    unsigned short* sB = lB(s);
    const bool pre = (tt + 2) < NT;

    bf16x8 af[4][2], bfr[2][2];
#pragma unroll
    for (int mi = 0; mi < 4; ++mi)
#pragma unroll
      for (int kk = 0; kk < 2; ++kk) af[mi][kk] = rdA(sA, mi, kk);
#pragma unroll
    for (int ni = 0; ni < 2; ++ni)
#pragma unroll
      for (int kk = 0; kk < 2; ++kk) bfr[ni][kk] = rdB(sB, ni, kk);
    if (pre) { stA(tt + 2, ns, 0); stA(tt + 2, ns, 1); stB(tt + 2, ns, 0); }
    pbar();
    __builtin_amdgcn_s_setprio(1);
#pragma unroll
    for (int kk = 0; kk < 2; ++kk)
#pragma unroll
      for (int mi = 0; mi < 4; ++mi)
#pragma unroll
        for (int ni = 0; ni < 2; ++ni)
          acc[mi][ni] = __builtin_amdgcn_mfma_f32_16x16x32_bf16(af[mi][kk], bfr[ni][kk],
                                                                acc[mi][ni], 0, 0, 0);
    __builtin_amdgcn_s_setprio(0);
    pbar();

#pragma unroll
    for (int ni = 0; ni < 2; ++ni)
#pragma unroll
      for (int kk = 0; kk < 2; ++kk) bfr[ni][kk] = rdB(sB, 2 + ni, kk);
    if (pre) { stB(tt + 2, ns, 1); stB(tt + 2, ns, 2); stB(tt + 2, ns, 3); }
    pbar();
    __builtin_amdgcn_s_setprio(1);
#pragma unroll
    for (int kk = 0; kk < 2; ++kk)
#pragma unroll
      for (int mi = 0; mi < 4; ++mi)
#pragma unroll
        for (int ni = 0; ni < 2; ++ni)
          acc[mi][2 + ni] = __builtin_amdgcn_mfma_f32_16x16x32_bf16(af[mi][kk], bfr[ni][kk],
                                                                    acc[mi][2 + ni], 0, 0, 0);
    __builtin_amdgcn_s_setprio(0);
    if (pre) vmwait6(); else vmwait0();
    pbar();
  }

#pragma unroll
  for (int mi = 0; mi < 4; ++mi)
#pragma unroll
    for (int nf = 0; nf < 4; ++nf)
#pragma unroll
      for (int r = 0; r < 4; ++r) {
        int row = m0 + wr * 64 + mi * 16 + g * 4 + r;
        int col = n0 + wc * 64 + nf * 16 + c;
        Out[(size_t)row * 2048 + col] = acc[mi][nf][r];
      }
}

// ---------------- flash attention: swapped QK^T + b64 packed P-writes ------
// (round-12 proven config: KVBLK=64, ones-MFMA denominator)
__global__ __launch_bounds__(256, 2)
void attn_kernel(const unsigned short* __restrict__ Qb,
                 const unsigned short* __restrict__ Kb,
                 const unsigned short* __restrict__ Vb,
                 unsigned short* __restrict__ Ob) {
  __shared__ unsigned short K_lds[64 * HEAD_D];
  __shared__ unsigned short V_lds[HEAD_D * 64];
  __shared__ unsigned short P_lds[4][32 * 64];

  const int t = threadIdx.x;
  const int w = t >> 6, l = t & 63;
  const int g = l >> 4, c = l & 15;

  const int bid = blockIdx.x;
  const int widx = (bid & 7) * 64 + (bid >> 3);
  const int bh = widx >> 4;
  const int q0 = (widx & 15) * 128;
  const int b = bh >> 4, h = bh & 15;
  const size_t base = (size_t)b * S_LEN * HID_DIM + (size_t)h * HEAD_D;
  const int qw = q0 + w * 32;

  bf16x8 qf[2][4];
#pragma unroll
  for (int qh = 0; qh < 2; ++qh) {
    const unsigned short* qp = Qb + base + (size_t)(qw + qh * 16 + c) * HID_DIM + g * 8;
#pragma unroll
    for (int dch = 0; dch < 4; ++dch) qf[qh][dch] = *(const bf16x8*)(qp + dch * 32);
  }

  f32x4 acc[2][8];
#pragma unroll
  for (int qh = 0; qh < 2; ++qh)
#pragma unroll
    for (int dc = 0; dc < 8; ++dc) acc[qh][dc] = (f32x4)0.0f;
  f32x4 asum[2];
  asum[0] = (f32x4)0.0f; asum[1] = (f32x4)0.0f;
  bf16x8 ones;
#pragma unroll
  for (int j = 0; j < 8; ++j) ones[j] = (short)0x3F80;  // bf16 1.0

  int kstart = q0 - (WIN - 1);
  if (kstart < 0) kstart = 0;
  kstart &= ~63;
  const int kend = q0 + 127;

  const float C1 = -1.0f / 3.0f;
  const float CE = SOFTCAP_F * 1.4426950408889634f;

  for (int k0 = kstart; k0 <= kend; k0 += 64) {
#pragma unroll
    for (int i = 0; i < 4; ++i) {
      int li = i * 256 + t;
      int row = li >> 4, chs = li & 15;
      int ch = chs ^ (row & 7);
      gload16(Kb + base + (size_t)(k0 + row) * HID_DIM + ch * 8, &K_lds[li * 8]);
    }
    {
      int m4 = t >> 4, ch = t & 15;
      const unsigned short* vg = Vb + base + (size_t)(k0 + 4 * m4) * HID_DIM + ch * 8;
      bf16x8 v0 = *(const bf16x8*)vg;
      bf16x8 v1 = *(const bf16x8*)(vg + HID_DIM);
      bf16x8 v2 = *(const bf16x8*)(vg + 2 * HID_DIM);
      bf16x8 v3 = *(const bf16x8*)(vg + 3 * HID_DIM);
#pragma unroll
      for (int j = 0; j < 8; ++j) {
        int d = ch * 8 + j;
        int sw = (j ^ ch) & 7;
        int e = (d * 64 + 4 * m4) ^ (sw << 3);
        unsigned long long val =
            (unsigned long long)(unsigned short)v0[j] |
            ((unsigned long long)(unsigned short)v1[j] << 16) |
            ((unsigned long long)(unsigned short)v2[j] << 32) |
            ((unsigned long long)(unsigned short)v3[j] << 48);
        *(unsigned long long*)&V_lds[e] = val;
      }
    }
    __syncthreads();

    if (k0 <= qw + 31 && k0 + 63 >= qw - (WIN - 1)) {
      // ---- QK^T SWAPPED: sc[qh][kc][r] = S[key = k0+kc*16+g*4+r][q = qw+qh*16+c]
      f32x4 sc[2][4];
#pragma unroll
      for (int qh = 0; qh < 2; ++qh)
#pragma unroll
        for (int kc = 0; kc < 4; ++kc) sc[qh][kc] = (f32x4)0.0f;
#pragma unroll
      for (int kc = 0; kc < 4; ++kc) {
#pragma unroll
        for (int dch = 0; dch < 4; ++dch) {
          int row = kc * 16 + c;
          int e = (row * HEAD_D + dch * 32 + g * 8) ^ ((row & 7) << 3);
          bf16x8 kf = *(const bf16x8*)&K_lds[e];
#pragma unroll
          for (int qh = 0; qh < 2; ++qh)
            sc[qh][kc] = __builtin_amdgcn_mfma_f32_16x16x32_bf16(kf, qf[qh][dch],
                                                                 sc[qh][kc], 0, 0, 0);
        }
      }
      // ---- softcap + mask + packed b64 P store ----
#pragma unroll
      for (int qh = 0; qh < 2; ++qh) {
        const int qwh = qw + qh * 16;
        const int i_g = qwh + c;
        const bool full = (k0 + 63 <= qwh) && (qwh + 15 - k0 < WIN);
        const int qq = qh * 16 + c;
#pragma unroll
        for (int kc = 0; kc < 4; ++kc) {
          unsigned u[4];
#pragma unroll
          for (int r = 0; r < 4; ++r) {
            float y = sc[qh][kc][r];
            float y2 = y * y;
            float tpoly = y * __builtin_fmaf(y2, C1, 1.0f);
            float pv = __builtin_amdgcn_exp2f(__builtin_fmaf(tpoly, CE, -CE));
            if (!full) {
              int j_g = k0 + kc * 16 + g * 4 + r;
              bool okm = (j_g <= i_g) && (i_g - j_g < WIN);
              pv = okm ? pv : 0.0f;
            }
            u[r] = __builtin_bit_cast(unsigned, pv);
          }
          unsigned w0 = (u[0] >> 16) | (u[1] & 0xFFFF0000u);
          unsigned w1 = (u[2] >> 16) | (u[3] & 0xFFFF0000u);
          int e = (qq * 64 + kc * 16 + g * 4) ^ ((qq & 7) << 3);
          *(unsigned long long*)&P_lds[w][e] =
              (unsigned long long)w0 | ((unsigned long long)w1 << 32);
        }
      }
      bf16x8 pa[2][2];
#pragma unroll
      for (int qh = 0; qh < 2; ++qh)
#pragma unroll
        for (int kb = 0; kb < 2; ++kb) {
          int row = qh * 16 + c;
          int e = (row * 64 + kb * 32 + g * 8) ^ ((row & 7) << 3);
          pa[qh][kb] = *(const bf16x8*)&P_lds[w][e];
        }
      // denominator: ones-column MFMA -> every lane gets the row sum
#pragma unroll
      for (int qh = 0; qh < 2; ++qh)
#pragma unroll
        for (int kb = 0; kb < 2; ++kb)
          asum[qh] = __builtin_amdgcn_mfma_f32_16x16x32_bf16(pa[qh][kb], ones,
                                                             asum[qh], 0, 0, 0);
#pragma unroll
      for (int dc = 0; dc < 8; ++dc) {
#pragma unroll
        for (int kb = 0; kb < 2; ++kb) {
          int d = dc * 16 + c;
          int sw = ((d & 7) ^ ((d >> 3) & 7)) & 7;
          int e = (d * 64 + kb * 32 + g * 8) ^ (sw << 3);
          bf16x8 vf = *(const bf16x8*)&V_lds[e];
#pragma unroll
          for (int qh = 0; qh < 2; ++qh)
            acc[qh][dc] = __builtin_amdgcn_mfma_f32_16x16x32_bf16(pa[qh][kb], vf,
                                                                  acc[qh][dc], 0, 0, 0);
        }
      }
    }
    __syncthreads();
  }

#pragma unroll
  for (int qh = 0; qh < 2; ++qh)
#pragma unroll
    for (int r = 0; r < 4; ++r) {
      float rinv = 1.0f / asum[qh][r];
#pragma unroll
      for (int dc = 0; dc < 8; ++dc) {
        int qq = qw + qh * 16 + g * 4 + r;
        float o = acc[qh][dc][r] * rinv;
        Ob[base + (size_t)qq * HID_DIM + dc * 16 + c] = f2bf(o);
      }
    }
}

// ---------------- host launch ----------------
extern "C" void kernel_launch(void* const* d_in, const int* in_sizes, int n_in,
                              void* d_out, int out_size, void* d_ws, size_t ws_size,
                              hipStream_t stream) {
  const float* x  = (const float*)d_in[0];
  const float* Wq = (const float*)d_in[1];
  const float* Wk = (const float*)d_in[2];
  const float* Wv = (const float*)d_in[3];
  const float* Wo = (const float*)d_in[4];

  const size_t NX = (size_t)M_ROWS * HID_DIM;    // 8,388,608
  const size_t NW = (size_t)HID_DIM * HID_DIM;   // 4,194,304

  unsigned short* xb  = (unsigned short*)d_ws;
  unsigned short* Wqb = xb + NX;
  unsigned short* Wkb = Wqb + NW;   // contiguous (fused-QKV B matrix)
  unsigned short* Wvb = Wkb + NW;
  unsigned short* Wob = Wvb + NW;
  unsigned short* Qb  = Wob + NW;   // Qb,Kb,Vb contiguous (QKV epilogue routing)
  unsigned short* Kb  = Qb + NX;
  unsigned short* Vb  = Kb + NX;
  unsigned short* Ab  = xb;         // reuse x_bf16 region for attn output

  // 1) fused conversion (flat launch, dst = xb|Wqb|Wkb|Wvb|Wob contiguous)
  cvt_all_kernel<<<dim3(12288), 256, 0, stream>>>(x, Wq, Wk, Wv, Wo, xb);

  // 2) fused QKV projection: [4096,2048] x [6144,2048]^T, 256 blocks = 1 round
  gemm_qkv_kernel<<<dim3(256), 512, 163840, stream>>>(xb, Wqb, Qb);

  // 3) attention (512 blocks, XCD-chunked inside)
  attn_kernel<<<dim3(512), 256, 0, stream>>>(Qb, Kb, Vb, Ab);

  // 4) output projection: 256 blocks = 1 round
  gemm_wo_kernel<<<dim3(256), 512, 147456, stream>>>(Ab, Wob, (float*)d_out);
}